// Round 18
// baseline (40.269 us; speedup 1.0000x reference)
//
#include <hip/hip_runtime.h>

// AliasFreeActivation, round 18: r13 wave-private barrier-free structure,
// f32 LDS (no cvt/pack/unpack) + filters via uniform scalar loads (SGPRs).
// r11 proved LDS bytes/conflicts are NOT the limiter, so f16 storage was
// pure instruction overhead (~90 VALU/lane) -- removed.
// x (2,256,84,84) f32 -> up x4 (24t) -> lrelu -> down x2 (12t) -> crop 10
// -> out (2,256,148,148) f32.
//
// Unit = (plane pz, band b 0..9, chunk c 0..2) per wave64, private 2048-dw
// f32 LDS slice, no __syncthreads. Band: out rows i0..i0+15, i0=min(16b,132)
// (band 9 overlaps band 8; duplicate stores bitwise-identical).
// Chunks: c0 g0..15 / out g8 0..6; c1 g14..29 / g8 7..13; c2 g28..38 / g8 14..18.
// LDS layout: row r = 128 floats; within each 8-col block, stored order is
// (c0,c4,c1,c5,c2,c6,c3,c7) -- i.e. col c at position 2*(c&3)+((c&7)>>2) --
// because P1's packed v2 results (a_c,b_c) store directly. P2 is
// column-independent (lane l owns stored pair (2l,2l+1)); P3 un-permutes at
// compile time (register renaming, zero instructions).
// P2: lane-per-pair fused up-v+lrelu+down-v, v2 f32 math, lane-local alias.
// Cross-lane handoffs ordered by s_waitcnt lgkmcnt(0) (lockstep wave).

typedef float v2 __attribute__((ext_vector_type(2)));

constexpr int IN_HW  = 84;
constexpr int OUT_HW = 148;
constexpr float SLOPE = 0.2f;

__device__ __forceinline__ void lds_fence() {
    asm volatile("s_waitcnt lgkmcnt(0)" ::: "memory");
}
__host__ __device__ constexpr int sidx(int c) {   // col -> stored position
    return (c & ~7) + 2 * (c & 3) + ((c & 7) >> 2);
}

template<int CHUNK>
__device__ __forceinline__ void wave_body(
    const float* __restrict__ xin, float* __restrict__ o,
    float* __restrict__ S, int l, int i0, int IR0,
    const float* fu, const float* fd)
{
    constexpr int G0  = (CHUNK == 0) ? 0 : (CHUNK == 1) ? 14 : 28;
    constexpr int NG  = (CHUNK == 2) ? 11 : 16;   // input col-groups
    constexpr int GO8 = (CHUNK == 0) ? 0 : (CHUNK == 1) ? 7 : 14;
    constexpr int NG8 = (CHUNK == 2) ? 5 : 7;     // output col-groups
    constexpr int NT1 = 16 * NG;
    constexpr int NT3 = 16 * NG8;

    // ---- P1: horizontal up-conv into private LDS slice ----
#pragma unroll
    for (int k = 0; k < (NT1 + 63) / 64; ++k) {
        int t = l + 64 * k;
        if (t < NT1) {
            int r = t / NG, gl = t - r * NG, g = G0 + gl;
            const float* xr = xin + (IR0 + r) * IN_HW + 2 * g;
            float2 p0 = *(const float2*)(xr);
            float2 p1 = *(const float2*)(xr + 2);
            float2 p2 = *(const float2*)(xr + 4);
            float2 p3 = *(const float2*)(xr + 6);
            float2 p4 = *(const float2*)(xr + ((g == 38) ? 6 : 8)); // OOB guard
            v2 V0 = {p0.y, p1.x};
            v2 V1 = {p1.x, p1.y};
            v2 V2 = {p1.y, p2.x};
            v2 V3 = {p2.x, p2.y};
            v2 V4 = {p2.y, p3.x};
            v2 V5 = {p3.x, p3.y};
            v2 V6 = {p3.y, p4.x};   // .y garbage only for g=38 tail (unused cols)
            v2 AB0 = V5*fu[1] + V4*fu[5] + V3*fu[9]  + V2*fu[13] + V1*fu[17] + V0*fu[21];
            v2 AB1 = V5*fu[2] + V4*fu[6] + V3*fu[10] + V2*fu[14] + V1*fu[18] + V0*fu[22];
            v2 AB2 = V5*fu[3] + V4*fu[7] + V3*fu[11] + V2*fu[15] + V1*fu[19] + V0*fu[23];
            v2 AB3 = V6*fu[0] + V5*fu[4] + V4*fu[8]  + V3*fu[12] + V2*fu[16] + V1*fu[20];
            float* dst = S + r * 128 + 8 * gl;
            *(float4*)(dst)     = make_float4(AB0.x, AB0.y, AB1.x, AB1.y);
            *(float4*)(dst + 4) = make_float4(AB2.x, AB2.y, AB3.x, AB3.y);
        }
    }
    lds_fence();                       // P1 writes visible to all lanes

    // ---- P2: lane-per-pair fused up-v + lrelu + down-v (v2 f32) ----
    {
        const float* up = S + 2 * l;
        v2 colv[16];
#pragma unroll
        for (int r = 0; r < 16; ++r) colv[r] = *(const v2*)&up[r * 128];
        v2 acc[16];
#pragma unroll
        for (int i = 0; i < 16; ++i) acc[i] = (v2)(0.0f);
#pragma unroll
        for (int t = 0; t < 42; ++t) {
            const int n  = (t + 1) >> 2;
            const int ph = (t + 1) & 3;
            v2 z = colv[n+5] * fu[ph];
            z += colv[n+4] * fu[ph+4];
            z += colv[n+3] * fu[ph+8];
            z += colv[n+2] * fu[ph+12];
            z += colv[n+1] * fu[ph+16];
            z += colv[n]   * fu[ph+20];
            z = __builtin_elementwise_max(z, z * SLOPE);   // lrelu
            const int m = t >> 1;
#pragma unroll
            for (int k = 0; k < 6; ++k) {                  // static after unroll
                const int li = m - k;
                if (li >= 0 && li < 16)
                    acc[li] += z * fd[(t & 1) ? (10 - 2*k) : (11 - 2*k)];
            }
        }
        float* tvc = S + 2 * l;         // same addrs this lane read: no hazard
#pragma unroll
        for (int i = 0; i < 16; ++i)
            *(v2*)&tvc[i * 128] = acc[i];
    }
    lds_fence();                       // P2 writes visible to all lanes

    // ---- P3: horizontal down-conv + store ----
#pragma unroll
    for (int k = 0; k < 2; ++k) {
        int t = l + 64 * k;
        if (t < NT3) {
            int i = t / NG8, gl8 = t - i * NG8;
            const float* base = S + i * 128 + 16 * gl8;
            float W[28];
#pragma unroll
            for (int kk = 0; kk < 7; ++kk)
                *(float4*)&W[4 * kk] = *(const float4*)(base + 4 * kk);
            float C[26];                             // un-permute: renaming only
#pragma unroll
            for (int c = 0; c < 26; ++c) C[c] = W[sidx(c)];
            v2 U[18];                                // U[t] = (col t, col t+8)
#pragma unroll
            for (int u = 0; u < 18; ++u)
                U[u] = (v2){ C[u], C[u + 8] };
            v2 q[4];
#pragma unroll
            for (int m = 0; m < 4; ++m) {
                v2 a = U[2 * m + 11] * fd[0];
#pragma unroll
                for (int u = 1; u < 12; ++u)
                    a += U[2 * m + 11 - u] * fd[u];
                q[m] = a;
            }
            const int g8g = GO8 + gl8;
            float* orow = o + (size_t)(i0 + i) * OUT_HW + 8 * g8g;
            *(float4*)(orow) = make_float4(q[0].x, q[1].x, q[2].x, q[3].x);
            if (g8g < 18)
                *(float4*)(orow + 4) = make_float4(q[0].y, q[1].y, q[2].y, q[3].y);
        }
    }
}

__global__ __launch_bounds__(256, 4) void afa_wave(
    const float* __restrict__ x, const float* __restrict__ ku,
    const float* __restrict__ kd, float* __restrict__ out)
{
    __shared__ __align__(16) float sb[4 * 2048];       // 32 KB: 4 wave slices
    const int lt = threadIdx.x;
    const int w  = lt >> 6;
    const int l  = lt & 63;
    float* S = sb + (w << 11);

    const int unit = blockIdx.x * 4 + w;               // 0..15359
    const int pz   = unit / 30;
    const int rem  = unit - 30 * pz;
    const int band = rem / 3;
    const int chunk = rem - 3 * band;
    const int i0   = (band == 9) ? 132 : 16 * band;
    const int IR0  = (i0 >> 1) + 1;

    // Uniform address -> scalar loads; filters live in SGPRs.
    float fu[24], fd[12];
#pragma unroll
    for (int i = 0; i < 24; ++i) fu[i] = ku[i];
#pragma unroll
    for (int i = 0; i < 12; ++i) fd[i] = kd[i];

    const float* xin = x + (size_t)pz * (IN_HW * IN_HW);
    float* o = out + (size_t)pz * (OUT_HW * OUT_HW);

    if (chunk == 0)      wave_body<0>(xin, o, S, l, i0, IR0, fu, fd);
    else if (chunk == 1) wave_body<1>(xin, o, S, l, i0, IR0, fu, fd);
    else                 wave_body<2>(xin, o, S, l, i0, IR0, fu, fd);
}

extern "C" void kernel_launch(void* const* d_in, const int* in_sizes, int n_in,
                              void* d_out, int out_size, void* d_ws, size_t ws_size,
                              hipStream_t stream) {
    const float* x  = (const float*)d_in[0];
    const float* ku = (const float*)d_in[1];
    const float* kd = (const float*)d_in[2];
    float* out = (float*)d_out;
    afa_wave<<<dim3(3840), dim3(256), 0, stream>>>(x, ku, kd, out);
}